// Round 1
// baseline (690.698 us; speedup 1.0000x reference)
//
#include <hip/hip_runtime.h>

#define SEQ    2048
#define DIM    2048              // D == N
#define NBATCH 4
#define MTOT   (NBATCH * SEQ)    // 8192
#define CHUNKS 32
#define CLEN   (SEQ / CHUNKS)    // 64

typedef __bf16 bf16_t;
typedef __bf16 bf16x8 __attribute__((ext_vector_type(8)));
typedef float  f32x4  __attribute__((ext_vector_type(4)));
typedef unsigned short u16x4 __attribute__((ext_vector_type(4)));

__device__ __forceinline__ unsigned short f2bf_rne(float f) {
    unsigned int u = __float_as_uint(f);
    u += 0x7fffu + ((u >> 16) & 1u);
    return (unsigned short)(u >> 16);
}

// ---------------- fp32 -> bf16 convert ----------------
__global__ void k_convert(const float* __restrict__ src,
                          unsigned short* __restrict__ dst, int n4) {
    int i = blockIdx.x * blockDim.x + threadIdx.x;
    if (i >= n4) return;
    f32x4 v = ((const f32x4*)src)[i];
    u16x4 o;
    o[0] = f2bf_rne(v[0]); o[1] = f2bf_rne(v[1]);
    o[2] = f2bf_rne(v[2]); o[3] = f2bf_rne(v[3]);
    ((u16x4*)dst)[i] = o;
}

// ---------------- bf16 NT-GEMM: C[M,N] = A[M,K] * Bm[N,K]^T (+ skip[n]*xres) ----
// 128x128 tile / block of 256 threads (4 waves, 2x2), each wave 64x64 via
// 4x4 grid of 16x16x32 MFMAs. BK=32. global_load_lds width-16 staging.
__global__ __launch_bounds__(256)
void k_gemm_bt(const bf16_t* __restrict__ A,   // [M,K] row-major
               const bf16_t* __restrict__ Bm,  // [N,K] row-major
               float* __restrict__ C,          // [M,N]
               int M, int N, int K,
               const float* __restrict__ skip,  // [N] or nullptr
               const float* __restrict__ xres)  // [M,N] or nullptr
{
    __shared__ __align__(16) bf16_t As[128 * 32];
    __shared__ __align__(16) bf16_t Bs[128 * 32];

    const int tid  = threadIdx.x;
    const int lane = tid & 63;
    const int wave = tid >> 6;
    const int wm   = wave >> 1;      // 0..1
    const int wn   = wave & 1;       // 0..1
    const int bm   = blockIdx.y;
    const int bn   = blockIdx.x;

    const int l15  = lane & 15;
    const int quad = lane >> 4;      // 0..3

    f32x4 acc[4][4];
#pragma unroll
    for (int i = 0; i < 4; i++)
#pragma unroll
        for (int j = 0; j < 4; j++) acc[i][j] = (f32x4){0.f, 0.f, 0.f, 0.f};

    // staging: each wave covers 32 rows of each tile in 2 calls of 16 rows
    const int srow = lane >> 2;         // 0..15 (row within a 16-row slab)
    const int scol = (lane & 3) * 8;    // k-offset in elements: 0,8,16,24
    const long arow0 = (long)bm * 128 + wave * 32;
    const long brow0 = (long)bn * 128 + wave * 32;

    for (int k0 = 0; k0 < K; k0 += 32) {
        __syncthreads();   // previous iteration's LDS reads complete
#pragma unroll
        for (int q = 0; q < 2; q++) {
            const bf16_t* ga = A  + (arow0 + q * 16 + srow) * (long)K + k0 + scol;
            __builtin_amdgcn_global_load_lds(
                (const __attribute__((address_space(1))) void*)ga,
                (__attribute__((address_space(3))) void*)((char*)As + (wave * 32 + q * 16) * 64),
                16, 0, 0);
            const bf16_t* gb = Bm + (brow0 + q * 16 + srow) * (long)K + k0 + scol;
            __builtin_amdgcn_global_load_lds(
                (const __attribute__((address_space(1))) void*)gb,
                (__attribute__((address_space(3))) void*)((char*)Bs + (wave * 32 + q * 16) * 64),
                16, 0, 0);
        }
        __syncthreads();   // drains vmcnt -> staging visible

        bf16x8 af[4], bf[4];
#pragma unroll
        for (int i = 0; i < 4; i++) {
            af[i] = *(const bf16x8*)(As + (wm * 64 + i * 16 + l15) * 32 + quad * 8);
            bf[i] = *(const bf16x8*)(Bs + (wn * 64 + i * 16 + l15) * 32 + quad * 8);
        }
#pragma unroll
        for (int i = 0; i < 4; i++)
#pragma unroll
            for (int j = 0; j < 4; j++)
                acc[i][j] = __builtin_amdgcn_mfma_f32_16x16x32_bf16(
                    af[i], bf[j], acc[i][j], 0, 0, 0);
    }

    // epilogue: C/D layout col=lane&15, row=quad*4+reg
#pragma unroll
    for (int i = 0; i < 4; i++) {
#pragma unroll
        for (int j = 0; j < 4; j++) {
#pragma unroll
            for (int r = 0; r < 4; r++) {
                long row = (long)bm * 128 + wm * 64 + i * 16 + quad * 4 + r;
                long col = (long)bn * 128 + wn * 64 + j * 16 + l15;
                long idx = row * (long)N + col;
                float v = acc[i][j][r];
                if (skip) v += skip[col] * xres[idx];
                C[idx] = v;
            }
        }
    }
}

// ---------------- elementwise: dt/softplus/exp ----------------
// in-place: dtp -> a = exp(dt * A), bp -> u = dt * Bp * x
__global__ void k_elemwise(float* __restrict__ dtp, float* __restrict__ bp,
                           const float* __restrict__ x,
                           const float* __restrict__ b_dt,
                           const float* __restrict__ A_log, int n4) {
    int i = blockIdx.x * blockDim.x + threadIdx.x;
    if (i >= n4) return;
    long e0 = (long)i * 4;
    int  n0 = (int)(e0 & (DIM - 1));
    f32x4 d    = ((const f32x4*)dtp)[i];
    f32x4 bv   = ((const f32x4*)bp)[i];
    f32x4 xv   = ((const f32x4*)x)[i];
    f32x4 bias = *(const f32x4*)(b_dt + n0);
    f32x4 al   = *(const f32x4*)(A_log + n0);
    f32x4 aout, uout;
#pragma unroll
    for (int k = 0; k < 4; k++) {
        float z  = d[k] + bias[k];
        float dt = (z > 15.f) ? z : log1pf(expf(z));   // softplus
        aout[k]  = expf(-expf(al[k]) * dt);            // A_bar
        uout[k]  = dt * bv[k] * xv[k];                 // dt * Bp * x
    }
    ((f32x4*)dtp)[i] = aout;
    ((f32x4*)bp)[i]  = uout;
}

// ---------------- chunked scan: h_t = a_t*h_{t-1} + u_t ----------------
// phase1: per (b,chunk,n): P = prod a, V = local scan end value (h_start=0)
__global__ void k_scan1(const float* __restrict__ a, const float* __restrict__ u,
                        float* __restrict__ P, float* __restrict__ V) {
    int t = blockIdx.x * blockDim.x + threadIdx.x;   // [b][c][n], 2^18 total
    int n = t & (DIM - 1);
    int c = (t >> 11) & (CHUNKS - 1);
    int b = t >> 16;
    long base = ((long)b * SEQ + (long)c * CLEN) * DIM + n;
    float p = 1.f, v = 0.f;
    for (int s = 0; s < CLEN; s++) {
        float av = a[base + (long)s * DIM];
        float uv = u[base + (long)s * DIM];
        v = av * v + uv;
        p *= av;
    }
    P[t] = p; V[t] = v;
}

// phase2: per (b,n): sequential scan over chunk carries
__global__ void k_scan2(const float* __restrict__ P, const float* __restrict__ V,
                        float* __restrict__ carry) {
    int t = blockIdx.x * blockDim.x + threadIdx.x;   // B*N = 8192
    int n = t & (DIM - 1);
    int b = t >> 11;
    float H = 0.f;
    for (int c = 0; c < CHUNKS; c++) {
        long idx = ((long)b * CHUNKS + c) * DIM + n;
        carry[idx] = H;
        H = P[idx] * H + V[idx];
    }
}

// phase3: replay chunk with true initial state; emit h as bf16
__global__ void k_scan3(const float* __restrict__ a, const float* __restrict__ u,
                        const float* __restrict__ carry,
                        unsigned short* __restrict__ h) {
    int t = blockIdx.x * blockDim.x + threadIdx.x;
    int n = t & (DIM - 1);
    int c = (t >> 11) & (CHUNKS - 1);
    int b = t >> 16;
    long base = ((long)b * SEQ + (long)c * CLEN) * DIM + n;
    float H = carry[t];
    for (int s = 0; s < CLEN; s++) {
        float av = a[base + (long)s * DIM];
        float uv = u[base + (long)s * DIM];
        H = av * H + uv;
        h[base + (long)s * DIM] = f2bf_rne(H);
    }
}

extern "C" void kernel_launch(void* const* d_in, const int* in_sizes, int n_in,
                              void* d_out, int out_size, void* d_ws, size_t ws_size,
                              hipStream_t stream) {
    const float* x      = (const float*)d_in[0];
    const float* W_dt   = (const float*)d_in[1];
    const float* b_dt   = (const float*)d_in[2];
    const float* W_B    = (const float*)d_in[3];
    const float* W_C    = (const float*)d_in[4];
    const float* A_log  = (const float*)d_in[5];
    const float* D_skip = (const float*)d_in[6];
    float* out = (float*)d_out;

    char* ws = (char*)d_ws;
    size_t off = 0;
    auto alloc = [&](size_t bytes) -> char* {
        char* p = ws + off;
        off += (bytes + 255) & ~(size_t)255;
        return p;
    };
    unsigned short* xb   = (unsigned short*)alloc((size_t)MTOT * DIM * 2); // reused as h_bf
    unsigned short* wdtb = (unsigned short*)alloc((size_t)DIM * DIM * 2);
    unsigned short* wbb  = (unsigned short*)alloc((size_t)DIM * DIM * 2);
    unsigned short* wcb  = (unsigned short*)alloc((size_t)DIM * DIM * 2);
    float* dtp   = (float*)alloc((size_t)MTOT * DIM * 4);  // -> a
    float* bp    = (float*)alloc((size_t)MTOT * DIM * 4);  // -> u
    float* P     = (float*)alloc((size_t)NBATCH * CHUNKS * DIM * 4);
    float* V     = (float*)alloc((size_t)NBATCH * CHUNKS * DIM * 4);
    float* carry = (float*)alloc((size_t)NBATCH * CHUNKS * DIM * 4);

    const int n4x = MTOT * DIM / 4;    // 4,194,304
    const int n4w = DIM * DIM / 4;     // 1,048,576
    k_convert<<<n4x / 256, 256, 0, stream>>>(x,    xb,   n4x);
    k_convert<<<n4w / 256, 256, 0, stream>>>(W_dt, wdtb, n4w);
    k_convert<<<n4w / 256, 256, 0, stream>>>(W_B,  wbb,  n4w);
    k_convert<<<n4w / 256, 256, 0, stream>>>(W_C,  wcb,  n4w);

    dim3 ggrid(DIM / 128, MTOT / 128);   // (16, 64)
    k_gemm_bt<<<ggrid, 256, 0, stream>>>((const bf16_t*)xb, (const bf16_t*)wdtb,
                                         dtp, MTOT, DIM, DIM, nullptr, nullptr);
    k_gemm_bt<<<ggrid, 256, 0, stream>>>((const bf16_t*)xb, (const bf16_t*)wbb,
                                         bp, MTOT, DIM, DIM, nullptr, nullptr);

    k_elemwise<<<n4x / 256, 256, 0, stream>>>(dtp, bp, x, b_dt, A_log, n4x);

    const int scan_threads = NBATCH * CHUNKS * DIM;   // 262144
    k_scan1<<<scan_threads / 256, 256, 0, stream>>>(dtp, bp, P, V);
    k_scan2<<<(NBATCH * DIM) / 256, 256, 0, stream>>>(P, V, carry);
    k_scan3<<<scan_threads / 256, 256, 0, stream>>>(dtp, bp, carry, xb /* h_bf */);

    k_gemm_bt<<<ggrid, 256, 0, stream>>>((const bf16_t*)xb, (const bf16_t*)wcb,
                                         out, MTOT, DIM, DIM, D_skip, x);
}